// Round 3
// baseline (1996.147 us; speedup 1.0000x reference)
//
#include <hip/hip_runtime.h>

#define TAILB 12.0f

__device__ __forceinline__ float softplus_f(float z) {
    // log1p(exp(z)); stable for large z. For very negative z, log1pf(exp(z)) ~ exp(z): fine.
    return (z > 15.f) ? z : log1pf(__expf(z));
}

// __launch_bounds__(256, 2): cap = 256 VGPRs (2 waves/SIMD). Round-1 default
// capped at ~104 VGPRs -> h1[128]+pr[46] spilled to scratch -> VALUBusy 45%.
// Live set here ~220 VGPRs: h1[128] + pr[46] + h2c[8] + ~40 temps/loads.
__global__ __launch_bounds__(256, 2)
void rqs_fused(const float* __restrict__ inp, const float* __restrict__ cond,
               const float* __restrict__ W1, const float* __restrict__ b1,
               const float* __restrict__ W2, const float* __restrict__ b2,
               const float* __restrict__ W3, const float* __restrict__ b3,
               float* __restrict__ out, int B)
{
    int tid = blockIdx.x * 256 + threadIdx.x;
    if (tid >= B) return;

    const float4 xi = reinterpret_cast<const float4*>(inp)[tid];
    float x0 = xi.x, x1 = xi.y, x2 = xi.z, x3 = xi.w;
    float c = cond[tid];
    float ld = 0.f;

    #pragma unroll 1
    for (int l = 0; l < 4; ++l) {
        // MASK_IDX: l0:(0,2) l1:(1,3) l2:(0,1) l3:(2,3)  (wave-uniform branches on l)
        float m0 = (l == 0 || l == 2) ? x0 : (l == 1) ? x1 : x2;
        float m1 = (l == 0) ? x2 : (l == 1) ? x3 : (l == 2) ? x1 : x3;

        const float* w1  = W1 + l * 384;     // [128,3]
        const float* bb1 = b1 + l * 128;
        const float* w2  = W2 + l * 16384;   // [128,128]
        const float* bb2 = b2 + l * 128;
        const float* w3  = W3 + l * 5888;    // [46,128]
        const float* bb3 = b3 + l * 46;

        // ---- phase 1: h1 = relu(W1 @ m + b1), fully in registers ----
        float h1[128];
        #pragma unroll
        for (int k = 0; k < 128; ++k) {
            float v = fmaf(w1[k * 3 + 0], m0,
                      fmaf(w1[k * 3 + 1], m1,
                      fmaf(w1[k * 3 + 2], c, bb1[k])));
            h1[k] = fmaxf(v, 0.f);
        }

        // ---- phase 2: h2 chunks of 8, consumed immediately into params[46] ----
        float pr[46];
        #pragma unroll
        for (int p = 0; p < 46; ++p) pr[p] = bb3[p];

        #pragma unroll 1
        for (int jc = 0; jc < 128; jc += 8) {
            float h2c[8];
            #pragma unroll
            for (int jj = 0; jj < 8; ++jj) {
                const float* wr = w2 + (jc + jj) * 128;
                float a = bb2[jc + jj];
                #pragma unroll
                for (int k = 0; k < 128; ++k) a = fmaf(wr[k], h1[k], a);
                h2c[jj] = fmaxf(a, 0.f);
            }
            #pragma unroll
            for (int p = 0; p < 46; ++p) {
                const float* wc = w3 + p * 128 + jc;
                float a = pr[p];
                #pragma unroll
                for (int jj = 0; jj < 8; ++jj) a = fmaf(wc[jj], h2c[jj], a);
                pr[p] = a;
            }
        }

        // ---- phase 3: RQS spline on the two transformed dims ----
        // tp[b,f,p] = params[b, p*2+f]; uw p=0..7, uh p=8..15, ud p=16..22
        float ynew[2];
        float ladsum = 0.f;
        #pragma unroll
        for (int f = 0; f < 2; ++f) {
            // INV_IDX: l0:(1,3) l1:(0,2) l2:(2,3) l3:(0,1)
            float xin;
            if (f == 0) xin = (l == 0) ? x1 : (l == 1) ? x0 : (l == 2) ? x2 : x0;
            else        xin = (l == 0) ? x3 : (l == 1) ? x2 : (l == 2) ? x3 : x1;

            float uw[8], uh[8];
            #pragma unroll
            for (int k = 0; k < 8; ++k) { uw[k] = pr[2 * k + f]; uh[k] = pr[16 + 2 * k + f]; }
            float d[9];
            d[0] = 1.f; d[8] = 1.f;   // softplus(log(exp(1-MIN_D)-1)) + MIN_D == 1.0 exactly
            #pragma unroll
            for (int k = 1; k < 8; ++k) d[k] = 1e-6f + softplus_f(pr[32 + 2 * (k - 1) + f]);

            bool inside = (xin >= -TAILB) && (xin <= TAILB);
            float xc = fminf(fmaxf(xin, -TAILB), TAILB);

            float mw = uw[0], mh = uh[0];
            #pragma unroll
            for (int k = 1; k < 8; ++k) { mw = fmaxf(mw, uw[k]); mh = fmaxf(mh, uh[k]); }
            float ew[8], eh[8], sw = 0.f, sh = 0.f;
            #pragma unroll
            for (int k = 0; k < 8; ++k) {
                ew[k] = __expf(uw[k] - mw); sw += ew[k];
                eh[k] = __expf(uh[k] - mh); sh += eh[k];
            }
            const float c1 = 1.f - 8e-6f;
            float isw = c1 / sw, ish = c1 / sh;

            // walk the 8 bins; select the last bin with xc >= cumw[k]
            float cum_w = 0.f, cum_h = 0.f;
            float cwk = -TAILB, chk = -TAILB;
            float s_cw = -TAILB, s_w = 2.f * TAILB, s_ch = -TAILB, s_h = 2.f * TAILB;
            float s_d0 = 1.f, s_d1 = d[1];
            #pragma unroll
            for (int k = 0; k < 8; ++k) {
                cum_w += fmaf(ew[k], isw, 1e-6f);
                cum_h += fmaf(eh[k], ish, 1e-6f);
                float cwn = (k == 7) ? TAILB : fmaf(2.f * TAILB, cum_w, -TAILB);
                float chn = (k == 7) ? TAILB : fmaf(2.f * TAILB, cum_h, -TAILB);
                bool ge = (xc >= cwk);
                s_cw = ge ? cwk : s_cw;  s_w = ge ? (cwn - cwk) : s_w;
                s_ch = ge ? chk : s_ch;  s_h = ge ? (chn - chk) : s_h;
                s_d0 = ge ? d[k] : s_d0; s_d1 = ge ? d[k + 1] : s_d1;
                cwk = cwn; chk = chn;
            }

            float th   = (xc - s_cw) / s_w;
            float delta = s_h / s_w;
            float omt  = 1.f - th;
            float tomt = th * omt;
            float num  = s_h * fmaf(delta, th * th, s_d0 * tomt);
            float den  = fmaf(s_d0 + s_d1 - 2.f * delta, tomt, delta);
            float y    = s_ch + num / den;
            float dnum = delta * delta * (s_d1 * th * th + 2.f * delta * tomt + s_d0 * omt * omt);
            float lad  = __logf(dnum) - 2.f * __logf(den);

            ynew[f] = inside ? y : xin;
            ladsum += inside ? lad : 0.f;
        }

        if (l == 0)      { x1 = ynew[0]; x3 = ynew[1]; }
        else if (l == 1) { x0 = ynew[0]; x2 = ynew[1]; }
        else if (l == 2) { x2 = ynew[0]; x3 = ynew[1]; }
        else             { x0 = ynew[0]; x1 = ynew[1]; }
        ld += ladsum;
    }

    float4 xo; xo.x = x0; xo.y = x1; xo.z = x2; xo.w = x3;
    reinterpret_cast<float4*>(out)[tid] = xo;
    out[(size_t)B * 4 + tid] = ld;
}

extern "C" void kernel_launch(void* const* d_in, const int* in_sizes, int n_in,
                              void* d_out, int out_size, void* d_ws, size_t ws_size,
                              hipStream_t stream) {
    const float* inp  = (const float*)d_in[0];
    const float* cond = (const float*)d_in[1];
    const float* W1   = (const float*)d_in[2];
    const float* b1   = (const float*)d_in[3];
    const float* W2   = (const float*)d_in[4];
    const float* b2   = (const float*)d_in[5];
    const float* W3   = (const float*)d_in[6];
    const float* b3   = (const float*)d_in[7];
    float* out = (float*)d_out;
    int B = in_sizes[0] / 4;
    int blocks = (B + 255) / 256;
    hipLaunchKernelGGL(rqs_fused, dim3(blocks), dim3(256), 0, stream,
                       inp, cond, W1, b1, W2, b2, W3, b3, out, B);
}

// Round 4
// 1811.448 us; speedup vs baseline: 1.1020x; 1.1020x over previous
//
#include <hip/hip_runtime.h>

#define TAILB 12.0f

__device__ __forceinline__ float softplus_f(float z) {
    return (z > 15.f) ? z : log1pf(__expf(z));
}

// Cooperative scheme: 64 samples/block, 256 threads (4 waves).
// h1/h2 [64 samples][128 feat] fp32 in LDS (shared across waves) -> no thread
// ever holds >32 accumulators, so nothing spills (round-1/3 lesson: the
// allocator refuses a 128-float live array, VGPR pinned at 100 w/ scratch).
// Weights are wave-uniform (readfirstlane'd base) -> scalar s_loads.
// LDS swizzle: dword-group g stored at g^(s&7) -> strided b128 ops spread
// over all 32 banks (lane stride = 512B would otherwise alias 1 bank).
__global__ __launch_bounds__(256, 3)
void rqs_coop(const float* __restrict__ inp, const float* __restrict__ cond,
              const float* __restrict__ W1, const float* __restrict__ b1,
              const float* __restrict__ W2, const float* __restrict__ b2,
              const float* __restrict__ W3, const float* __restrict__ b3,
              float* __restrict__ out, int B)
{
    __shared__ __align__(16) float hbuf[64 * 128];   // h1 then h2 (reused), swizzled
    __shared__ float pbuf[48 * 65];                  // params [p][sample]
    __shared__ float xbuf[64][9];                    // x0..x3, c (stride 9: bank spread)
    __shared__ float ladbuf[2][64];
    __shared__ float ldacc[64];

    const int tid  = threadIdx.x;
    const int s    = tid & 63;        // sample in block (lane id)
    const int w    = tid >> 6;        // wave 0..3
    const int sw   = s & 7;           // swizzle key
    const int base = blockIdx.x * 64;

    if (tid < 64) {
        float4 xi = reinterpret_cast<const float4*>(inp)[base + tid];
        xbuf[tid][0] = xi.x; xbuf[tid][1] = xi.y;
        xbuf[tid][2] = xi.z; xbuf[tid][3] = xi.w;
        xbuf[tid][4] = cond[base + tid];
        ldacc[tid] = 0.f;
    }
    __syncthreads();

    #pragma unroll 1
    for (int l = 0; l < 4; ++l) {
        int mi0, mi1, ii0, ii1;
        switch (l) {
            case 0:  mi0 = 0; mi1 = 2; ii0 = 1; ii1 = 3; break;
            case 1:  mi0 = 1; mi1 = 3; ii0 = 0; ii1 = 2; break;
            case 2:  mi0 = 0; mi1 = 1; ii0 = 2; ii1 = 3; break;
            default: mi0 = 2; mi1 = 3; ii0 = 0; ii1 = 1; break;
        }

        // ---- phase 1: h1[s][k] for k in [32w, 32w+32), write swizzled ----
        {
            float m0 = xbuf[s][mi0], m1 = xbuf[s][mi1], cc = xbuf[s][4];
            const float* w1l = W1 + l * 384;
            const float* b1l = b1 + l * 128;
            int kb = __builtin_amdgcn_readfirstlane(32 * w);
            #pragma unroll
            for (int gi = 0; gi < 8; ++gi) {
                int g = (kb >> 2) + gi;          // logical dword-group (uniform)
                float4 v;
                float* vp = &v.x;
                #pragma unroll
                for (int j = 0; j < 4; ++j) {
                    int k = 4 * g + j;
                    float t = fmaf(w1l[k * 3 + 0], m0,
                              fmaf(w1l[k * 3 + 1], m1,
                              fmaf(w1l[k * 3 + 2], cc, b1l[k])));
                    vp[j] = fmaxf(t, 0.f);
                }
                *reinterpret_cast<float4*>(&hbuf[s * 128 + ((g ^ sw) << 2)]) = v;
            }
        }
        __syncthreads();

        // ---- phase 2: wave w computes h2[s][n], n in [32w,32w+32), 2 passes of 16 ----
        float h2v[32];
        {
            const float* w2l = W2 + l * 16384;
            const float* b2l = b2 + l * 128;
            int nbase = __builtin_amdgcn_readfirstlane(32 * w);
            #pragma unroll 1
            for (int half = 0; half < 2; ++half) {
                int nb = nbase + 16 * half;
                float acc[16];
                #pragma unroll
                for (int i = 0; i < 16; ++i) acc[i] = b2l[nb + i];
                #pragma unroll 1
                for (int gc = 0; gc < 32; ++gc) {        // k ascending (round-1 order)
                    float4 hv = *reinterpret_cast<const float4*>(
                        &hbuf[s * 128 + ((gc ^ sw) << 2)]);
                    const float* wp = w2l + gc * 4;
                    #pragma unroll
                    for (int i = 0; i < 16; ++i) {
                        const float* wr = wp + (nb + i) * 128;
                        acc[i] = fmaf(wr[0], hv.x, acc[i]);
                        acc[i] = fmaf(wr[1], hv.y, acc[i]);
                        acc[i] = fmaf(wr[2], hv.z, acc[i]);
                        acc[i] = fmaf(wr[3], hv.w, acc[i]);
                    }
                }
                #pragma unroll
                for (int i = 0; i < 16; ++i)
                    h2v[16 * half + i] = fmaxf(acc[i], 0.f);
            }
        }
        __syncthreads();   // all h1 reads done before overwrite

        // write h2 into hbuf (same swizzle): n = 32w + 4gi + j
        {
            int nb = __builtin_amdgcn_readfirstlane(32 * w);
            #pragma unroll
            for (int gi = 0; gi < 8; ++gi) {
                int g = (nb >> 2) + gi;
                float4 v;
                v.x = h2v[4 * gi]; v.y = h2v[4 * gi + 1];
                v.z = h2v[4 * gi + 2]; v.w = h2v[4 * gi + 3];
                *reinterpret_cast<float4*>(&hbuf[s * 128 + ((g ^ sw) << 2)]) = v;
            }
        }
        __syncthreads();

        // ---- phase 3: wave w computes params p in [12w, 12w+12) (wave 3: 10) ----
        {
            const float* w3l = W3 + l * 5888;
            const float* b3l = b3 + l * 46;
            int pbase = __builtin_amdgcn_readfirstlane(12 * w);
            float pacc[12];
            #pragma unroll
            for (int i = 0; i < 12; ++i) {
                int p = pbase + i;
                pacc[i] = b3l[p < 46 ? p : 45];
            }
            #pragma unroll 1
            for (int gc = 0; gc < 32; ++gc) {            // n ascending (round-1 order)
                float4 hv = *reinterpret_cast<const float4*>(
                    &hbuf[s * 128 + ((gc ^ sw) << 2)]);
                #pragma unroll
                for (int i = 0; i < 12; ++i) {
                    int p = pbase + i;
                    const float* wr = w3l + (p < 46 ? p : 45) * 128 + gc * 4;
                    pacc[i] = fmaf(wr[0], hv.x, pacc[i]);
                    pacc[i] = fmaf(wr[1], hv.y, pacc[i]);
                    pacc[i] = fmaf(wr[2], hv.z, pacc[i]);
                    pacc[i] = fmaf(wr[3], hv.w, pacc[i]);
                }
            }
            #pragma unroll
            for (int i = 0; i < 12; ++i) {
                int p = pbase + i;
                if (p < 46) pbuf[p * 65 + s] = pacc[i];
            }
        }
        __syncthreads();

        // ---- phase 4: spline, thread (f = tid>>6, ss = tid&63), 128 threads ----
        if (tid < 128) {
            int f = tid >> 6, ss = tid & 63;
            float pr[23];    // params of parity f: uw pr[0..7], uh pr[8..15], ud pr[16..22]
            #pragma unroll
            for (int i = 0; i < 23; ++i) pr[i] = pbuf[(2 * i + f) * 65 + ss];

            float xin = xbuf[ss][f == 0 ? ii0 : ii1];

            float d[9];
            d[0] = 1.f; d[8] = 1.f;
            #pragma unroll
            for (int k = 1; k < 8; ++k) d[k] = 1e-6f + softplus_f(pr[16 + k - 1]);

            bool inside = (xin >= -TAILB) && (xin <= TAILB);
            float xc = fminf(fmaxf(xin, -TAILB), TAILB);

            float mw = pr[0], mh = pr[8];
            #pragma unroll
            for (int k = 1; k < 8; ++k) { mw = fmaxf(mw, pr[k]); mh = fmaxf(mh, pr[8 + k]); }
            float ew[8], eh[8], swm = 0.f, shm = 0.f;
            #pragma unroll
            for (int k = 0; k < 8; ++k) {
                ew[k] = __expf(pr[k] - mw);     swm += ew[k];
                eh[k] = __expf(pr[8 + k] - mh); shm += eh[k];
            }
            const float c1 = 1.f - 8e-6f;
            float isw = c1 / swm, ish = c1 / shm;

            float cum_w = 0.f, cum_h = 0.f;
            float cwk = -TAILB, chk = -TAILB;
            float s_cw = -TAILB, s_w = 2.f * TAILB, s_ch = -TAILB, s_h = 2.f * TAILB;
            float s_d0 = 1.f, s_d1 = d[1];
            #pragma unroll
            for (int k = 0; k < 8; ++k) {
                cum_w += fmaf(ew[k], isw, 1e-6f);
                cum_h += fmaf(eh[k], ish, 1e-6f);
                float cwn = (k == 7) ? TAILB : fmaf(2.f * TAILB, cum_w, -TAILB);
                float chn = (k == 7) ? TAILB : fmaf(2.f * TAILB, cum_h, -TAILB);
                bool ge = (xc >= cwk);
                s_cw = ge ? cwk : s_cw;  s_w = ge ? (cwn - cwk) : s_w;
                s_ch = ge ? chk : s_ch;  s_h = ge ? (chn - chk) : s_h;
                s_d0 = ge ? d[k] : s_d0; s_d1 = ge ? d[k + 1] : s_d1;
                cwk = cwn; chk = chn;
            }

            float th    = (xc - s_cw) / s_w;
            float delta = s_h / s_w;
            float omt   = 1.f - th;
            float tomt  = th * omt;
            float num   = s_h * fmaf(delta, th * th, s_d0 * tomt);
            float den   = fmaf(s_d0 + s_d1 - 2.f * delta, tomt, delta);
            float y     = s_ch + num / den;
            float dnum  = delta * delta * (s_d1 * th * th + 2.f * delta * tomt + s_d0 * omt * omt);
            float lad   = __logf(dnum) - 2.f * __logf(den);

            xbuf[ss][f == 0 ? ii0 : ii1] = inside ? y : xin;
            ladbuf[f][ss] = inside ? lad : 0.f;
        }
        __syncthreads();
        if (tid < 64) ldacc[tid] += ladbuf[0][tid] + ladbuf[1][tid];
        // next-layer phase 1 only reads xbuf (synced); ladbuf rewritten only
        // after the next spline's preceding barriers -> no extra barrier here.
    }

    if (tid < 64) {
        float4 xo;
        xo.x = xbuf[tid][0]; xo.y = xbuf[tid][1];
        xo.z = xbuf[tid][2]; xo.w = xbuf[tid][3];
        reinterpret_cast<float4*>(out)[base + tid] = xo;
        out[(size_t)B * 4 + base + tid] = ldacc[tid];
    }
}

extern "C" void kernel_launch(void* const* d_in, const int* in_sizes, int n_in,
                              void* d_out, int out_size, void* d_ws, size_t ws_size,
                              hipStream_t stream) {
    const float* inp  = (const float*)d_in[0];
    const float* cond = (const float*)d_in[1];
    const float* W1   = (const float*)d_in[2];
    const float* b1   = (const float*)d_in[3];
    const float* W2   = (const float*)d_in[4];
    const float* b2   = (const float*)d_in[5];
    const float* W3   = (const float*)d_in[6];
    const float* b3   = (const float*)d_in[7];
    float* out = (float*)d_out;
    int B = in_sizes[0] / 4;
    hipLaunchKernelGGL(rqs_coop, dim3(B / 64), dim3(256), 0, stream,
                       inp, cond, W1, b1, W2, b2, W3, b3, out, B);
}

// Round 5
// 755.823 us; speedup vs baseline: 2.6410x; 2.3967x over previous
//
#include <hip/hip_runtime.h>

#define TAILB 12.0f

__device__ __forceinline__ float softplus_f(float z) {
    return (z > 15.f) ? z : log1pf(__expf(z));
}

// ---------------- prep: repack weights into per-wave-contiguous chunks ----------------
// ws layout:
//   W2P @0      : 65536 dwords (256 KB)  [slab(l,nh,w)][kc 0..31][64 dw: n=i>>2, k=i&3]
//   W3P @262144 : 24576 dwords (96 KB)   [slab(l,nh,w)][nc 0..15][48 dw: p=i>>2, n=i&3]
//   w1p @360448 : 512 float4 (8 KB)      [l][k] = {W1[k][0..2], b1[k]}
__global__ __launch_bounds__(256)
void prep_v5(const float* __restrict__ W1, const float* __restrict__ b1,
             const float* __restrict__ W2, const float* __restrict__ W3,
             float* __restrict__ W2P, float* __restrict__ W3P, float4* __restrict__ w1p)
{
    int id = blockIdx.x * 256 + threadIdx.x;
    if (id < 65536) {
        int c = id >> 6, i = id & 63;
        int slab = c >> 5, kc = c & 31;
        int l = slab >> 3, nh = (slab >> 2) & 1, w = slab & 3;
        int n = 64 * nh + 16 * w + (i >> 2);
        int k = 4 * kc + (i & 3);
        W2P[id] = W2[l * 16384 + n * 128 + k];
    } else if (id < 65536 + 24576) {
        int t = id - 65536;
        int c = t / 48, i = t % 48;
        int slab = c >> 4, nc = c & 15;
        int l = slab >> 3, nh = (slab >> 2) & 1, w = slab & 3;
        int p = 12 * w + (i >> 2);
        int n = 64 * nh + 4 * nc + (i & 3);
        W3P[t] = (p < 46) ? W3[l * 5888 + p * 128 + n] : 0.f;
    } else if (id < 65536 + 24576 + 512) {
        int t = id - 90112;
        int l = t >> 7, k = t & 127;
        float4 v;
        v.x = W1[l * 384 + k * 3 + 0];
        v.y = W1[l * 384 + k * 3 + 1];
        v.z = W1[l * 384 + k * 3 + 2];
        v.w = b1[l * 128 + k];
        w1p[t] = v;
    }
}

// 128 samples/block, 256 threads (4 waves). Lane ln covers samples ln and ln+64.
// h1 staged in k-quarters (recomputed per n-half: cheap), h2 in n-halves.
// Weights: prep-packed 256B/192B chunks, uniform (readfirstlane base) -> s_load
// batches hoisted before the FMA block. Max per-thread array = 16 floats x2.
__global__ __launch_bounds__(256, 2)
void rqs_v5(const float* __restrict__ inp, const float* __restrict__ cond,
            const float* __restrict__ W2P, const float* __restrict__ W3P,
            const float4* __restrict__ w1p,
            const float* __restrict__ b2, const float* __restrict__ b3,
            float* __restrict__ out, int B)
{
    __shared__ __align__(16) float hbuf[128 * 32];    // h1 k-quarter [s][kk], xor-swizzled
    __shared__ __align__(16) float h2buf[128 * 64];   // h2 n-half [s][nn]; pbuf overlays
    __shared__ float xbuf[128][6];                    // x0..x3, c
    __shared__ float ladb[2][128];
    __shared__ float ldacc[128];

    const int tid  = threadIdx.x;
    const int w    = tid >> 6;
    const int ln   = tid & 63;
    const int base = blockIdx.x * 128;
    float* pbuf = h2buf;                              // overlay: [48][129]

    if (tid < 128) {
        float4 xi = reinterpret_cast<const float4*>(inp)[base + tid];
        xbuf[tid][0] = xi.x; xbuf[tid][1] = xi.y;
        xbuf[tid][2] = xi.z; xbuf[tid][3] = xi.w;
        xbuf[tid][4] = cond[base + tid];
        ldacc[tid] = 0.f;
    }
    __syncthreads();

    #pragma unroll 1
    for (int l = 0; l < 4; ++l) {
        int mi0, mi1, ii0, ii1;
        switch (l) {
            case 0:  mi0 = 0; mi1 = 2; ii0 = 1; ii1 = 3; break;
            case 1:  mi0 = 1; mi1 = 3; ii0 = 0; ii1 = 2; break;
            case 2:  mi0 = 0; mi1 = 1; ii0 = 2; ii1 = 3; break;
            default: mi0 = 2; mi1 = 3; ii0 = 0; ii1 = 1; break;
        }

        // GEMM3 accumulators (live across whole layer): p = 12w + i
        float pacc0[12], pacc1[12];
        {
            int pb = __builtin_amdgcn_readfirstlane(l * 46 + 12 * w);
            #pragma unroll
            for (int i = 0; i < 12; ++i) {
                float bv = (12 * w + i < 46) ? b3[pb + i] : 0.f;
                pacc0[i] = bv; pacc1[i] = bv;
            }
        }

        #pragma unroll 1
        for (int nh = 0; nh < 2; ++nh) {
            // GEMM2 accumulators: n = 64nh + 16w + j
            float acc0[16], acc1[16];
            {
                int nb = __builtin_amdgcn_readfirstlane(l * 128 + 64 * nh + 16 * w);
                #pragma unroll
                for (int j = 0; j < 16; ++j) {
                    float bv = b2[nb + j];
                    acc0[j] = bv; acc1[j] = bv;
                }
            }

            #pragma unroll 1
            for (int kq = 0; kq < 4; ++kq) {
                __syncthreads();   // prior hbuf readers done
                // ---- phase 1: h1[s][k], k in [32kq, +32); thread: s=tid&127, half=tid>>7
                {
                    int s = tid & 127;
                    int khh = __builtin_amdgcn_readfirstlane(tid >> 7);
                    float m0 = xbuf[s][mi0], m1 = xbuf[s][mi1], cc = xbuf[s][4];
                    int sw7 = s & 7;
                    const float4* w1l = w1p + l * 128;
                    #pragma unroll
                    for (int gi = 0; gi < 4; ++gi) {
                        int g = khh * 4 + gi;
                        float4 v;
                        float* vp = &v.x;
                        #pragma unroll
                        for (int j = 0; j < 4; ++j) {
                            int k = kq * 32 + g * 4 + j;
                            float4 wv = w1l[k];
                            float t = fmaf(wv.x, m0, fmaf(wv.y, m1, fmaf(wv.z, cc, wv.w)));
                            vp[j] = fmaxf(t, 0.f);
                        }
                        *reinterpret_cast<float4*>(&hbuf[s * 32 + ((g ^ sw7) << 2)]) = v;
                    }
                }
                __syncthreads();

                // ---- GEMM2: 8 chunks of 4k x 16n; weights hoisted per chunk ----
                {
                    int slabbase = __builtin_amdgcn_readfirstlane(
                        (((l * 2 + nh) * 4 + w) * 32 + kq * 8) * 64);
                    const float* wc = W2P + slabbase;
                    int sw7 = ln & 7;
                    #pragma unroll 1
                    for (int ck = 0; ck < 8; ++ck) {
                        const float4* wq = reinterpret_cast<const float4*>(wc + ck * 64);
                        float4 wv[16];
                        #pragma unroll
                        for (int j = 0; j < 16; ++j) wv[j] = wq[j];
                        float4 a0 = *reinterpret_cast<const float4*>(
                            &hbuf[ln * 32 + ((ck ^ sw7) << 2)]);
                        float4 a1 = *reinterpret_cast<const float4*>(
                            &hbuf[(ln + 64) * 32 + ((ck ^ sw7) << 2)]);
                        #pragma unroll
                        for (int j = 0; j < 16; ++j) {
                            acc0[j] = fmaf(wv[j].x, a0.x, acc0[j]);
                            acc0[j] = fmaf(wv[j].y, a0.y, acc0[j]);
                            acc0[j] = fmaf(wv[j].z, a0.z, acc0[j]);
                            acc0[j] = fmaf(wv[j].w, a0.w, acc0[j]);
                            acc1[j] = fmaf(wv[j].x, a1.x, acc1[j]);
                            acc1[j] = fmaf(wv[j].y, a1.y, acc1[j]);
                            acc1[j] = fmaf(wv[j].z, a1.z, acc1[j]);
                            acc1[j] = fmaf(wv[j].w, a1.w, acc1[j]);
                        }
                    }
                }
            } // kq

            __syncthreads();   // protect h2buf/pbuf WAR (prev nh GEMM3 / prev spline reads)
            // ---- epilogue: h2 = relu(acc), write n-half to h2buf ----
            {
                int sw15 = ln & 15;
                #pragma unroll
                for (int gi = 0; gi < 4; ++gi) {
                    int g = 4 * w + gi;
                    float4 v0, v1;
                    v0.x = fmaxf(acc0[4 * gi + 0], 0.f); v1.x = fmaxf(acc1[4 * gi + 0], 0.f);
                    v0.y = fmaxf(acc0[4 * gi + 1], 0.f); v1.y = fmaxf(acc1[4 * gi + 1], 0.f);
                    v0.z = fmaxf(acc0[4 * gi + 2], 0.f); v1.z = fmaxf(acc1[4 * gi + 2], 0.f);
                    v0.w = fmaxf(acc0[4 * gi + 3], 0.f); v1.w = fmaxf(acc1[4 * gi + 3], 0.f);
                    *reinterpret_cast<float4*>(&h2buf[ln * 64 + ((g ^ sw15) << 2)]) = v0;
                    *reinterpret_cast<float4*>(&h2buf[(ln + 64) * 64 + ((g ^ sw15) << 2)]) = v1;
                }
            }
            __syncthreads();

            // ---- GEMM3: 16 chunks of 4n x 12p over this n-half ----
            {
                int slabbase = __builtin_amdgcn_readfirstlane(
                    (((l * 2 + nh) * 4 + w) * 16) * 48);
                const float* wc = W3P + slabbase;
                int sw15 = ln & 15;
                #pragma unroll 1
                for (int nc = 0; nc < 16; ++nc) {
                    const float4* wq = reinterpret_cast<const float4*>(wc + nc * 48);
                    float4 wv[12];
                    #pragma unroll
                    for (int i = 0; i < 12; ++i) wv[i] = wq[i];
                    float4 a0 = *reinterpret_cast<const float4*>(
                        &h2buf[ln * 64 + ((nc ^ sw15) << 2)]);
                    float4 a1 = *reinterpret_cast<const float4*>(
                        &h2buf[(ln + 64) * 64 + ((nc ^ sw15) << 2)]);
                    #pragma unroll
                    for (int i = 0; i < 12; ++i) {
                        pacc0[i] = fmaf(wv[i].x, a0.x, pacc0[i]);
                        pacc0[i] = fmaf(wv[i].y, a0.y, pacc0[i]);
                        pacc0[i] = fmaf(wv[i].z, a0.z, pacc0[i]);
                        pacc0[i] = fmaf(wv[i].w, a0.w, pacc0[i]);
                        pacc1[i] = fmaf(wv[i].x, a1.x, pacc1[i]);
                        pacc1[i] = fmaf(wv[i].y, a1.y, pacc1[i]);
                        pacc1[i] = fmaf(wv[i].z, a1.z, pacc1[i]);
                        pacc1[i] = fmaf(wv[i].w, a1.w, pacc1[i]);
                    }
                }
            }
        } // nh

        __syncthreads();   // all GEMM3 h2buf reads done -> pbuf overlay safe
        #pragma unroll
        for (int i = 0; i < 12; ++i) {
            int p = 12 * w + i;
            if (p < 46) {
                pbuf[p * 129 + ln]      = pacc0[i];
                pbuf[p * 129 + ln + 64] = pacc1[i];
            }
        }
        __syncthreads();

        // ---- spline: thread (f = tid>>7, s = tid&127) — all 256 threads ----
        {
            int f = tid >> 7, s = tid & 127;
            float pr[23];
            #pragma unroll
            for (int i = 0; i < 23; ++i) pr[i] = pbuf[(2 * i + f) * 129 + s];

            float xin = xbuf[s][f == 0 ? ii0 : ii1];

            float d[9];
            d[0] = 1.f; d[8] = 1.f;
            #pragma unroll
            for (int k = 1; k < 8; ++k) d[k] = 1e-6f + softplus_f(pr[16 + k - 1]);

            bool inside = (xin >= -TAILB) && (xin <= TAILB);
            float xc = fminf(fmaxf(xin, -TAILB), TAILB);

            float mw = pr[0], mh = pr[8];
            #pragma unroll
            for (int k = 1; k < 8; ++k) { mw = fmaxf(mw, pr[k]); mh = fmaxf(mh, pr[8 + k]); }
            float ew[8], eh[8], swm = 0.f, shm = 0.f;
            #pragma unroll
            for (int k = 0; k < 8; ++k) {
                ew[k] = __expf(pr[k] - mw);     swm += ew[k];
                eh[k] = __expf(pr[8 + k] - mh); shm += eh[k];
            }
            const float c1 = 1.f - 8e-6f;
            float isw = c1 / swm, ish = c1 / shm;

            float cum_w = 0.f, cum_h = 0.f;
            float cwk = -TAILB, chk = -TAILB;
            float s_cw = -TAILB, s_w = 2.f * TAILB, s_ch = -TAILB, s_h = 2.f * TAILB;
            float s_d0 = 1.f, s_d1 = d[1];
            #pragma unroll
            for (int k = 0; k < 8; ++k) {
                cum_w += fmaf(ew[k], isw, 1e-6f);
                cum_h += fmaf(eh[k], ish, 1e-6f);
                float cwn = (k == 7) ? TAILB : fmaf(2.f * TAILB, cum_w, -TAILB);
                float chn = (k == 7) ? TAILB : fmaf(2.f * TAILB, cum_h, -TAILB);
                bool ge = (xc >= cwk);
                s_cw = ge ? cwk : s_cw;  s_w = ge ? (cwn - cwk) : s_w;
                s_ch = ge ? chk : s_ch;  s_h = ge ? (chn - chk) : s_h;
                s_d0 = ge ? d[k] : s_d0; s_d1 = ge ? d[k + 1] : s_d1;
                cwk = cwn; chk = chn;
            }

            float th    = (xc - s_cw) / s_w;
            float delta = s_h / s_w;
            float omt   = 1.f - th;
            float tomt  = th * omt;
            float num   = s_h * fmaf(delta, th * th, s_d0 * tomt);
            float den   = fmaf(s_d0 + s_d1 - 2.f * delta, tomt, delta);
            float y     = s_ch + num / den;
            float dnum  = delta * delta * (s_d1 * th * th + 2.f * delta * tomt + s_d0 * omt * omt);
            float lad   = __logf(dnum) - 2.f * __logf(den);

            xbuf[s][f == 0 ? ii0 : ii1] = inside ? y : xin;
            ladb[f][s] = inside ? lad : 0.f;
        }
        __syncthreads();
        if (tid < 128) ldacc[tid] += ladb[0][tid] + ladb[1][tid];
        __syncthreads();
    } // l

    if (tid < 128) {
        float4 xo;
        xo.x = xbuf[tid][0]; xo.y = xbuf[tid][1];
        xo.z = xbuf[tid][2]; xo.w = xbuf[tid][3];
        reinterpret_cast<float4*>(out)[base + tid] = xo;
        out[(size_t)B * 4 + base + tid] = ldacc[tid];
    }
}

extern "C" void kernel_launch(void* const* d_in, const int* in_sizes, int n_in,
                              void* d_out, int out_size, void* d_ws, size_t ws_size,
                              hipStream_t stream) {
    const float* inp  = (const float*)d_in[0];
    const float* cond = (const float*)d_in[1];
    const float* W1   = (const float*)d_in[2];
    const float* b1   = (const float*)d_in[3];
    const float* W2   = (const float*)d_in[4];
    const float* b2   = (const float*)d_in[5];
    const float* W3   = (const float*)d_in[6];
    const float* b3   = (const float*)d_in[7];
    float* out = (float*)d_out;
    int B = in_sizes[0] / 4;

    float*  W2P = (float*)d_ws;                          // 262144 B
    float*  W3P = (float*)((char*)d_ws + 262144);        // 98304 B
    float4* w1p = (float4*)((char*)d_ws + 360448);       // 8192 B

    hipLaunchKernelGGL(prep_v5, dim3(360), dim3(256), 0, stream,
                       W1, b1, W2, W3, W2P, W3P, w1p);
    hipLaunchKernelGGL(rqs_v5, dim3(B / 128), dim3(256), 0, stream,
                       inp, cond, W2P, W3P, w1p, b2, b3, out, B);
}